// Round 2
// baseline (366.362 us; speedup 1.0000x reference)
//
#include <hip/hip_runtime.h>
#include <hip/hip_fp16.h>

#define D 128

// CSR build geometry (pow-2 so kernels use shifts, not divides)
constexpr int RSH = 14;             // log2(range size)
constexpr int RSZ = 1 << RSH;       // 16384 nodes/range
constexpr int NRANGE = 4;           // ceil(50000/16384)
constexpr int CSH = 15;             // log2(chunk edges)
constexpr int CSZ = 1 << CSH;       // 32768 edges/chunk

using short8 = __attribute__((ext_vector_type(8))) short;
using f32x4 = __attribute__((ext_vector_type(4))) float;

// split fp32 into hi/lo bf16 (truncation; residual exact in fp32)
__device__ inline void splitf(float v, unsigned short& h, unsigned short& l) {
    unsigned b = __float_as_uint(v);
    h = (unsigned short)(b >> 16);
    float fh = __uint_as_float(b & 0xffff0000u);
    float r = v - fh;
    l = (unsigned short)(__float_as_uint(r) >> 16);
}

// ---------------- CSR build: rank-based counting sort ----------------
// R11: hist pass records per-edge rank within its (range,chunk,node) cell, so the
// fill pass is edge-parallel with no LDS/atomics and reads each edge ONCE
// (old fill_part read dst 8x = 22.4MB extra). Hist uses packed-u16 LDS counts
// (counts <= chunk size 32768 < 65536), NRANGE=4 -> dst read 4x not 8x, and the
// u16 hist array halves deg/scan traffic.

__global__ __launch_bounds__(1024) void hist_rank(
    const int* __restrict__ dst, unsigned* __restrict__ hist,
    unsigned short* __restrict__ rank, int n_edges, int nchunk) {
    __shared__ unsigned lh[RSZ / 2];   // 16384 u16 counts packed in 8192 words, 32KB
    int b = blockIdx.x;
    int r = b & (NRANGE - 1), c = b >> 2;
    int t = threadIdx.x;
    for (int i = t; i < RSZ / 2; i += 1024) lh[i] = 0;
    __syncthreads();
    int e0 = c << CSH, e1 = min(n_edges, e0 + CSZ);
    for (int e = e0 + t; e < e1; e += 1024) {
        int d = dst[e];
        if ((d >> RSH) == r) {
            int ii = d & (RSZ - 1);
            unsigned sh = (ii & 1) * 16;
            unsigned old = atomicAdd(&lh[ii >> 1], 1u << sh);
            rank[e] = (unsigned short)((old >> sh) & 0xffffu);
        }
    }
    __syncthreads();
    unsigned* gh = hist + (size_t)(r * nchunk + c) * (RSZ / 2);
    for (int i = t; i < RSZ / 2; i += 1024) gh[i] = lh[i];
}

// ---------------- weight split+transpose args ----------------
struct WSplitArgs {
    const float* src[6];
    unsigned short* dh[6];
    unsigned short* dl[6];
};

// deg[i] = sum over chunks (u16 hist); block emits partial sum for the scan.
// Blocks >= nblk do the weight split+transpose (fused: saves a dispatch).
__global__ __launch_bounds__(256) void deg_splitw(
    const unsigned short* __restrict__ hist16, int* __restrict__ deg,
    int* __restrict__ partials, int n_nodes, int nchunk, int nblk, WSplitArgs a) {
    __shared__ int sd[256];
    int b = blockIdx.x, t = threadIdx.x;
    if (b >= nblk) {
        // weight split: mats 0-3 are 128x128 (16384 el), mats 4-5 are 128x64 (8192 el)
        int g = (b - nblk) * 256 + t;
        int m, e, N;
        if (g < 65536) { m = g >> 14; e = g & 16383; N = 128; }
        else { int t2 = g - 65536; m = 4 + (t2 >> 13); e = t2 & 8191; N = 64; }
        int sh = (N == 128) ? 7 : 6;
        int k = e >> sh;
        int n = e & (N - 1);
        float v = a.src[m][e];
        unsigned short h, l;
        splitf(v, h, l);
        a.dh[m][n * 128 + k] = h;
        a.dl[m][n * 128 + k] = l;
        return;
    }
    int i = b * 256 + t;
    int s = 0;
    if (i < n_nodes) {
        int r = i >> RSH, ii = i & (RSZ - 1);
        const unsigned short* hp = hist16 + (size_t)r * nchunk * RSZ + ii;
        for (int c = 0; c < nchunk; ++c) s += hp[(size_t)c * RSZ];
        deg[i] = s;
    }
    sd[t] = s;
    __syncthreads();
    for (int st = 128; st > 0; st >>= 1) {
        if (t < st) sd[t] += sd[t + st];
        __syncthreads();
    }
    if (t == 0) partials[b] = sd[0];
}

// One block per 256 nodes: reduce partials locally, Hillis-Steele scan of deg,
// emit row_ptr + inv_deg, and fill base[] (per-cell exclusive offsets) in one pass.
__global__ __launch_bounds__(256) void scan_fill(
    const int* __restrict__ deg, const int* __restrict__ partials,
    const unsigned short* __restrict__ hist16, int* __restrict__ row_ptr,
    float* __restrict__ inv_deg, int* __restrict__ base,
    int n_nodes, int nchunk, int nblk) {
    __shared__ int sp[256];
    __shared__ int sd[256];
    int b = blockIdx.x, t = threadIdx.x;

    sp[t] = (t < b && t < nblk) ? partials[t] : 0;
    __syncthreads();
    for (int st = 128; st > 0; st >>= 1) {
        if (t < st) sp[t] += sp[t + st];
        __syncthreads();
    }
    int pbase = sp[0];

    int i = b * 256 + t;
    int v = (i < n_nodes) ? deg[i] : 0;
    sd[t] = v;
    __syncthreads();
    for (int d = 1; d < 256; d <<= 1) {
        int x = (t >= d) ? sd[t - d] : 0;
        __syncthreads();
        sd[t] += x;
        __syncthreads();
    }
    int excl = sd[t] - v + pbase;
    if (i < n_nodes) {
        row_ptr[i] = excl;
        int dv = v > 1 ? v : 1;
        inv_deg[i] = 1.0f / (float)dv;
        if (i == n_nodes - 1) row_ptr[n_nodes] = excl + v;
        int r = i >> RSH, ii = i & (RSZ - 1);
        int bacc = excl;
        for (int c = 0; c < nchunk; ++c) {
            size_t idx = (size_t)(r * nchunk + c) * RSZ + ii;
            base[idx] = bacc;
            bacc += hist16[idx];
        }
    }
}

// Edge-parallel, atomic-free fill: slot = base[cell] + rank[e].
__global__ __launch_bounds__(256) void fill_edges(
    const int* __restrict__ src, const int* __restrict__ dst,
    const unsigned short* __restrict__ rank, const int* __restrict__ base,
    int* __restrict__ csr, int n_edges, int nchunk) {
    int e = blockIdx.x * 256 + threadIdx.x;
    if (e >= n_edges) return;
    int d = dst[e];
    int c = e >> CSH;
    int r = d >> RSH;
    int slot = base[(size_t)(r * nchunk + c) * RSZ + (d & (RSZ - 1))] + rank[e];
    csr[slot] = src[e];
}

// ---------------- layer-0 MFMA GEMM (x fp32 -> P,Q) ----------------
// BM=64 rows/block, 4 waves. A staged in LDS as bf16 hi/lo (split during staging).
// Wave w: matrix = w>>1 (0->P via W1, 1->Q via W2), col half = w&1.
// LDS layout [col16][row] stride 65 -> conflict-free ds_read_b128.
__global__ __launch_bounds__(256) void gemm_x(
    const float* __restrict__ X,
    const unsigned short* __restrict__ W1h, const unsigned short* __restrict__ W1l,
    const unsigned short* __restrict__ W2h, const unsigned short* __restrict__ W2l,
    const float* __restrict__ bias, __half* __restrict__ P, float* __restrict__ Q, int M) {
    __shared__ short8 As[2][16 * 65];   // 33.3 KB

    const int tid = threadIdx.x;
    const int wave = tid >> 6;
    const int lane = tid & 63;
    const int l15 = lane & 15;
    const int q = lane >> 4;
    const int m0 = blockIdx.x * 64;

#pragma unroll
    for (int it = 0; it < 4; ++it) {
        int s = it * 256 + tid;          // 0..1023
        int row = s >> 4, col16 = s & 15;
        int gr = min(m0 + row, M - 1);
        const float4* xp = (const float4*)X + (size_t)gr * 32 + col16 * 2;
        float4 v0 = xp[0], v1 = xp[1];
        float fv[8] = {v0.x, v0.y, v0.z, v0.w, v1.x, v1.y, v1.z, v1.w};
        short8 h, l;
#pragma unroll
        for (int j = 0; j < 8; ++j) {
            unsigned short hh_, ll_;
            splitf(fv[j], hh_, ll_);
            h[j] = (short)hh_;
            l[j] = (short)ll_;
        }
        As[0][col16 * 65 + row] = h;
        As[1][col16 * 65 + row] = l;
    }
    __syncthreads();

    const int isQ = wave >> 1;
    const int colbase = (wave & 1) * 64;
    const unsigned short* Wh = isQ ? W2h : W1h;
    const unsigned short* Wl = isQ ? W2l : W1l;

    float bvs[4];
#pragma unroll
    for (int nt = 0; nt < 4; ++nt) bvs[nt] = isQ ? bias[colbase + nt * 16 + l15] : 0.f;

    f32x4 acc[4][4] = {};

#pragma unroll 1
    for (int kt = 0; kt < 4; ++kt) {
        short8 Bh[4], Bl[4];
#pragma unroll
        for (int nt = 0; nt < 4; ++nt) {
            int c = colbase + nt * 16 + l15;
            int off = c * 128 + kt * 32 + q * 8;
            Bh[nt] = *(const short8*)(Wh + off);
            Bl[nt] = *(const short8*)(Wl + off);
        }
#pragma unroll
        for (int mt = 0; mt < 4; ++mt) {
            int ai = (kt * 4 + q) * 65 + mt * 16 + l15;
            short8 Afh = As[0][ai];
            short8 Afl = As[1][ai];
#pragma unroll
            for (int nt = 0; nt < 4; ++nt) {
                acc[mt][nt] = __builtin_amdgcn_mfma_f32_16x16x32_bf16(Afh, Bh[nt], acc[mt][nt], 0, 0, 0);
                acc[mt][nt] = __builtin_amdgcn_mfma_f32_16x16x32_bf16(Afh, Bl[nt], acc[mt][nt], 0, 0, 0);
                acc[mt][nt] = __builtin_amdgcn_mfma_f32_16x16x32_bf16(Afl, Bh[nt], acc[mt][nt], 0, 0, 0);
            }
        }
    }

#pragma unroll
    for (int mt = 0; mt < 4; ++mt) {
        int orow = m0 + mt * 16 + q * 4;
#pragma unroll
        for (int nt = 0; nt < 4; ++nt) {
            int col = colbase + nt * 16 + l15;
#pragma unroll
            for (int r = 0; r < 4; ++r) {
                int rr = orow + r;
                if (rr < M) {
                    if (isQ) Q[(size_t)rr * 128 + col] = acc[mt][nt][r] + bvs[nt];
                    else P[(size_t)rr * 128 + col] = __float2half(acc[mt][nt][r]);
                }
            }
        }
    }
}

// ---------------- merged agg + GEMM ----------------
// R11: each block gathers its own 64 nodes (H' = relu(mean P + Q), hi/lo split)
// straight into the GEMM's LDS A-tile -- eliminates the hh/hl global round trip
// (51.2MB) and 2 dispatches. Gather phase: wave w owns rows w*16..w*16+15
// sequentially, same 4-edge-slot x 16-lane structure as the old agg kernel.
// In-flight bytes (16 waves/CU x ~6KB) keep the gather L3-BW-bound, not
// latency-bound, despite lower TLP than the standalone agg.
template <int BN, int NT>
__global__ __launch_bounds__(256) void agg_gemm(
    const __half* __restrict__ Pprev, const float* __restrict__ Qprev,
    const int* __restrict__ row_ptr, const int* __restrict__ csr,
    const float* __restrict__ inv_deg,
    const unsigned short* __restrict__ W1h, const unsigned short* __restrict__ W1l,
    const unsigned short* __restrict__ W2h, const unsigned short* __restrict__ W2l,
    const float* __restrict__ bias, __half* __restrict__ P, float* __restrict__ Q, int M) {
    __shared__ short8 As[2][16 * 65];   // 33.3 KB

    const int tid = threadIdx.x;
    const int wave = tid >> 6;
    const int lane = tid & 63;
    const int l15 = lane & 15;
    const int q = lane >> 4;            // GEMM quad; also edge slot in gather
    const int m0 = blockIdx.x * 64;

    // ---- gather + relu + split phase ----
#pragma unroll 1
    for (int i = 0; i < 16; ++i) {
        int row = (wave << 4) + i;
        int node = m0 + row;
        bool valid = node < M;
        float a[2][8] = {};
        if (valid) {
            int beg = row_ptr[node], end = row_ptr[node + 1];
            int e = beg;
            for (; e + 8 <= end; e += 8) {
#pragma unroll
                for (int j = 0; j < 2; ++j) {
                    int s = csr[e + 4 * j + q];
                    uint4 raw = *(const uint4*)(Pprev + (size_t)s * 128 + l15 * 8);
                    float2 f01 = __half22float2(*reinterpret_cast<__half2*>(&raw.x));
                    float2 f23 = __half22float2(*reinterpret_cast<__half2*>(&raw.y));
                    float2 f45 = __half22float2(*reinterpret_cast<__half2*>(&raw.z));
                    float2 f67 = __half22float2(*reinterpret_cast<__half2*>(&raw.w));
                    a[j][0] += f01.x; a[j][1] += f01.y; a[j][2] += f23.x; a[j][3] += f23.y;
                    a[j][4] += f45.x; a[j][5] += f45.y; a[j][6] += f67.x; a[j][7] += f67.y;
                }
            }
            for (; e < end; e += 4) {
                int idx = e + q;
                if (idx < end) {
                    int s = csr[idx];
                    uint4 raw = *(const uint4*)(Pprev + (size_t)s * 128 + l15 * 8);
                    float2 f01 = __half22float2(*reinterpret_cast<__half2*>(&raw.x));
                    float2 f23 = __half22float2(*reinterpret_cast<__half2*>(&raw.y));
                    float2 f45 = __half22float2(*reinterpret_cast<__half2*>(&raw.z));
                    float2 f67 = __half22float2(*reinterpret_cast<__half2*>(&raw.w));
                    a[0][0] += f01.x; a[0][1] += f01.y; a[0][2] += f23.x; a[0][3] += f23.y;
                    a[0][4] += f45.x; a[0][5] += f45.y; a[0][6] += f67.x; a[0][7] += f67.y;
                }
            }
        }
        float s8[8];
#pragma unroll
        for (int k = 0; k < 8; ++k) {
            s8[k] = a[0][k] + a[1][k];
            s8[k] += __shfl_xor(s8[k], 16);
            s8[k] += __shfl_xor(s8[k], 32);
        }
        if (lane < 16) {
            short8 h8 = {}, l8 = {};
            if (valid) {
                float w = inv_deg[node];
                const float4* Q4 = (const float4*)Qprev;
                float4 q0 = Q4[(size_t)node * 32 + 2 * l15];
                float4 q1 = Q4[(size_t)node * 32 + 2 * l15 + 1];
                float hv[8];
                hv[0] = fmaxf(fmaf(s8[0], w, q0.x), 0.f);
                hv[1] = fmaxf(fmaf(s8[1], w, q0.y), 0.f);
                hv[2] = fmaxf(fmaf(s8[2], w, q0.z), 0.f);
                hv[3] = fmaxf(fmaf(s8[3], w, q0.w), 0.f);
                hv[4] = fmaxf(fmaf(s8[4], w, q1.x), 0.f);
                hv[5] = fmaxf(fmaf(s8[5], w, q1.y), 0.f);
                hv[6] = fmaxf(fmaf(s8[6], w, q1.z), 0.f);
                hv[7] = fmaxf(fmaf(s8[7], w, q1.w), 0.f);
#pragma unroll
                for (int k = 0; k < 8; ++k) {
                    unsigned short hh_, ll_;
                    splitf(hv[k], hh_, ll_);
                    h8[k] = (short)hh_;
                    l8[k] = (short)ll_;
                }
            }
            As[0][l15 * 65 + row] = h8;
            As[1][l15 * 65 + row] = l8;
        }
    }
    __syncthreads();

    // ---- GEMM phase ----
    const int isQ = wave >> 1;
    const int colbase = (wave & 1) * (NT * 16);
    const unsigned short* Wh = isQ ? W2h : W1h;
    const unsigned short* Wl = isQ ? W2l : W1l;

    float bvs[NT];
#pragma unroll
    for (int nt = 0; nt < NT; ++nt) bvs[nt] = isQ ? bias[colbase + nt * 16 + l15] : 0.f;

    f32x4 acc[4][NT] = {};

#pragma unroll 1
    for (int kt = 0; kt < 4; ++kt) {
        short8 Bh[NT], Bl[NT];
#pragma unroll
        for (int nt = 0; nt < NT; ++nt) {
            int c = colbase + nt * 16 + l15;
            int off = c * 128 + kt * 32 + q * 8;
            Bh[nt] = *(const short8*)(Wh + off);
            Bl[nt] = *(const short8*)(Wl + off);
        }
#pragma unroll
        for (int mt = 0; mt < 4; ++mt) {
            int ai = (kt * 4 + q) * 65 + mt * 16 + l15;
            short8 Afh = As[0][ai];
            short8 Afl = As[1][ai];
#pragma unroll
            for (int nt = 0; nt < NT; ++nt) {
                acc[mt][nt] = __builtin_amdgcn_mfma_f32_16x16x32_bf16(Afh, Bh[nt], acc[mt][nt], 0, 0, 0);
                acc[mt][nt] = __builtin_amdgcn_mfma_f32_16x16x32_bf16(Afh, Bl[nt], acc[mt][nt], 0, 0, 0);
                acc[mt][nt] = __builtin_amdgcn_mfma_f32_16x16x32_bf16(Afl, Bh[nt], acc[mt][nt], 0, 0, 0);
            }
        }
    }

#pragma unroll
    for (int mt = 0; mt < 4; ++mt) {
        int orow = m0 + mt * 16 + q * 4;
#pragma unroll
        for (int nt = 0; nt < NT; ++nt) {
            int col = colbase + nt * 16 + l15;
#pragma unroll
            for (int r = 0; r < 4; ++r) {
                int rr = orow + r;
                if (rr < M) {
                    if (isQ) Q[(size_t)rr * BN + col] = acc[mt][nt][r] + bvs[nt];
                    else P[(size_t)rr * BN + col] = __float2half(acc[mt][nt][r]);
                }
            }
        }
    }
}

// ---------------- fused aggregation 64-dim (fp16 gather) + output head ----------------
__global__ __launch_bounds__(256) void agg64_head(
    const __half* __restrict__ P, const float* __restrict__ Q,
    const int* __restrict__ row_ptr, const int* __restrict__ csr,
    const float* __restrict__ inv_deg, const float* __restrict__ Wo,
    const float* __restrict__ bo, float* __restrict__ out, int n_nodes) {
    int node = (blockIdx.x * blockDim.x + threadIdx.x) >> 6;
    int lane = threadIdx.x & 63;
    if (node >= n_nodes) return;
    int beg = row_ptr[node], end = row_ptr[node + 1];
    const int quarter = lane >> 4;
    const int l = lane & 15;
    float a[2][4] = {};
    int e = beg;
    for (; e + 8 <= end; e += 8) {
#pragma unroll
        for (int j = 0; j < 2; ++j) {
            int s = csr[e + 4 * j + quarter];
            uint2 raw = *(const uint2*)(P + (size_t)s * 64 + l * 4);
            float2 f01 = __half22float2(*reinterpret_cast<__half2*>(&raw.x));
            float2 f23 = __half22float2(*reinterpret_cast<__half2*>(&raw.y));
            a[j][0] += f01.x; a[j][1] += f01.y; a[j][2] += f23.x; a[j][3] += f23.y;
        }
    }
    for (; e < end; e += 4) {
        int idx = e + quarter;
        if (idx < end) {
            int s = csr[idx];
            uint2 raw = *(const uint2*)(P + (size_t)s * 64 + l * 4);
            float2 f01 = __half22float2(*reinterpret_cast<__half2*>(&raw.x));
            float2 f23 = __half22float2(*reinterpret_cast<__half2*>(&raw.y));
            a[0][0] += f01.x; a[0][1] += f01.y; a[0][2] += f23.x; a[0][3] += f23.y;
        }
    }
    float s0 = a[0][0] + a[1][0];
    float s1 = a[0][1] + a[1][1];
    float s2 = a[0][2] + a[1][2];
    float s3 = a[0][3] + a[1][3];
    s0 += __shfl_xor(s0, 16); s0 += __shfl_xor(s0, 32);
    s1 += __shfl_xor(s1, 16); s1 += __shfl_xor(s1, 32);
    s2 += __shfl_xor(s2, 16); s2 += __shfl_xor(s2, 32);
    s3 += __shfl_xor(s3, 16); s3 += __shfl_xor(s3, 32);
    if (lane < 16) {
        float w = inv_deg[node];
        float4 qv = ((const float4*)Q)[(size_t)node * 16 + l];
        float h0 = fmaxf(fmaf(s0, w, qv.x), 0.f);
        float h1 = fmaxf(fmaf(s1, w, qv.y), 0.f);
        float h2 = fmaxf(fmaf(s2, w, qv.z), 0.f);
        float h3 = fmaxf(fmaf(s3, w, qv.w), 0.f);
        const float4* Wo4 = (const float4*)Wo;
        float4 w0 = Wo4[4 * l + 0], w1 = Wo4[4 * l + 1], w2 = Wo4[4 * l + 2], w3 = Wo4[4 * l + 3];
        float c0 = h0 * w0.x + h1 * w1.x + h2 * w2.x + h3 * w3.x;
        float c1 = h0 * w0.y + h1 * w1.y + h2 * w2.y + h3 * w3.y;
        float c2 = h0 * w0.z + h1 * w1.z + h2 * w2.z + h3 * w3.z;
        float c3 = h0 * w0.w + h1 * w1.w + h2 * w2.w + h3 * w3.w;
#pragma unroll
        for (int m = 8; m > 0; m >>= 1) {
            c0 += __shfl_xor(c0, m);
            c1 += __shfl_xor(c1, m);
            c2 += __shfl_xor(c2, m);
            c3 += __shfl_xor(c3, m);
        }
        if (l == 0) {
            float4 r;
            r.x = c0 + bo[0];
            r.y = c1 + bo[1];
            r.z = c2 + bo[2];
            r.w = c3 + bo[3];
            ((float4*)out)[node] = r;
        }
    }
}

extern "C" void kernel_launch(void* const* d_in, const int* in_sizes, int n_in,
                              void* d_out, int out_size, void* d_ws, size_t ws_size,
                              hipStream_t stream) {
    const float* x = (const float*)d_in[0];
    const int* ei = (const int*)d_in[1];
    const float* wl0 = (const float*)d_in[3];
    const float* wr0 = (const float*)d_in[4];
    const float* b0 = (const float*)d_in[5];
    const float* wl1 = (const float*)d_in[6];
    const float* wr1 = (const float*)d_in[7];
    const float* b1 = (const float*)d_in[8];
    const float* wl2 = (const float*)d_in[9];
    const float* wr2 = (const float*)d_in[10];
    const float* b2 = (const float*)d_in[11];
    const float* wo = (const float*)d_in[12];
    const float* bo = (const float*)d_in[13];

    const int n_nodes = in_sizes[0] / D;   // 50000
    const int n_edges = in_sizes[1] / 2;   // 800000
    const int* srcp = ei;
    const int* dstp = ei + n_edges;

    char* ws = (char*)d_ws;
    size_t off = 0;
    auto carve = [&](size_t bytes) -> void* {
        void* p = ws + off;
        off = (off + bytes + 255) & ~(size_t)255;
        return p;
    };
    int* deg = (int*)carve((size_t)n_nodes * 4);
    int* row_ptr = (int*)carve((size_t)(n_nodes + 1) * 4);
    int* partials = (int*)carve(256 * 4);
    float* inv_deg = (float*)carve((size_t)n_nodes * 4);
    unsigned short* rankb = (unsigned short*)carve((size_t)n_edges * 2);
    int* csr = (int*)carve((size_t)n_edges * 4);
    __half* Pa = (__half*)carve((size_t)n_nodes * D * 2);     // 12.8 MB
    float* Qa = (float*)carve((size_t)n_nodes * D * 4);       // 25.6 MB
    __half* Pb = (__half*)carve((size_t)n_nodes * D * 2);     // 12.8 MB
    float* Qb = (float*)carve((size_t)n_nodes * D * 4);       // 25.6 MB
    unsigned short* wt = (unsigned short*)carve((size_t)(4 * 128 * 128 + 2 * 64 * 128) * 2 * 2);
    unsigned short* wl0h = wt;
    unsigned short* wl0l = wl0h + 128 * 128;
    unsigned short* wr0h = wl0l + 128 * 128;
    unsigned short* wr0l = wr0h + 128 * 128;
    unsigned short* wl1h = wr0l + 128 * 128;
    unsigned short* wl1l = wl1h + 128 * 128;
    unsigned short* wr1h = wl1l + 128 * 128;
    unsigned short* wr1l = wr1h + 128 * 128;
    unsigned short* wl2h = wr1l + 128 * 128;
    unsigned short* wl2l = wl2h + 64 * 128;
    unsigned short* wr2h = wl2l + 64 * 128;
    unsigned short* wr2l = wr2h + 64 * 128;

    // CSR-build scratch aliases Pa/Qa (dead until gemm_x):
    const int nchunk = (n_edges + CSZ - 1) >> CSH;          // 25
    unsigned* hist = (unsigned*)Qa;                          // 4*25*16384*2B = 3.28 MB
    unsigned short* hist16 = (unsigned short*)Qa;
    int* basep = (int*)Pa;                                   // 4*25*16384*4B = 6.55 MB

    const int nblk = (n_nodes + 255) / 256;                 // 196
    const int wblocks = (4 * 128 * 128 + 2 * 64 * 128) / 256;  // 320

    WSplitArgs wa;
    wa.src[0] = wl0; wa.dh[0] = wl0h; wa.dl[0] = wl0l;
    wa.src[1] = wr0; wa.dh[1] = wr0h; wa.dl[1] = wr0l;
    wa.src[2] = wl1; wa.dh[2] = wl1h; wa.dl[2] = wl1l;
    wa.src[3] = wr1; wa.dh[3] = wr1h; wa.dl[3] = wr1l;
    wa.src[4] = wl2; wa.dh[4] = wl2h; wa.dl[4] = wl2l;
    wa.src[5] = wr2; wa.dh[5] = wr2h; wa.dl[5] = wr2l;

    hist_rank<<<NRANGE * nchunk, 1024, 0, stream>>>(dstp, hist, rankb, n_edges, nchunk);
    deg_splitw<<<nblk + wblocks, 256, 0, stream>>>(hist16, deg, partials, n_nodes, nchunk, nblk, wa);
    scan_fill<<<nblk, 256, 0, stream>>>(deg, partials, hist16, row_ptr, inv_deg, basep,
                                        n_nodes, nchunk, nblk);
    fill_edges<<<(n_edges + 255) / 256, 256, 0, stream>>>(srcp, dstp, rankb, basep, csr,
                                                          n_edges, nchunk);

    const int gemm_blocks = (n_nodes + 63) / 64;   // 782
    const int agg_blocks = (n_nodes * 64 + 255) / 256;

    // layer 0: x -> P0,Q0 (runs after fill_edges: basep aliases Pa)
    gemm_x<<<gemm_blocks, 256, 0, stream>>>(x, wl0h, wl0l, wr0h, wr0l, b0, Pa, Qa, n_nodes);
    // layer 1: gather P0/Q0 -> H1 (in LDS) -> P1,Q1
    agg_gemm<128, 4><<<gemm_blocks, 256, 0, stream>>>(
        Pa, Qa, row_ptr, csr, inv_deg, wl1h, wl1l, wr1h, wr1l, b1, Pb, Qb, n_nodes);
    // layer 2: gather P1/Q1 -> H2 -> P2,Q2 (64 cols each)
    agg_gemm<64, 2><<<gemm_blocks, 256, 0, stream>>>(
        Pb, Qb, row_ptr, csr, inv_deg, wl2h, wl2l, wr2h, wr2l, b2, Pa, (float*)Qa, n_nodes);
    // head: gather P2/Q2 -> out
    agg64_head<<<agg_blocks, 256, 0, stream>>>(Pa, (const float*)Qa, row_ptr, csr, inv_deg,
                                               wo, bo, (float*)d_out, n_nodes);
}

// Round 3
// 306.513 us; speedup vs baseline: 1.1953x; 1.1953x over previous
//
#include <hip/hip_runtime.h>
#include <hip/hip_fp16.h>

#define D 128

// CSR build geometry (pow-2 so kernels use shifts, not divides)
constexpr int RSH = 14;             // log2(range size)
constexpr int RSZ = 1 << RSH;       // 16384 nodes/range
constexpr int NRANGE = 4;           // ceil(50000/16384)
constexpr int CSH = 15;             // log2(chunk edges)
constexpr int CSZ = 1 << CSH;       // 32768 edges/chunk

using short8 = __attribute__((ext_vector_type(8))) short;
using f32x4 = __attribute__((ext_vector_type(4))) float;

// split fp32 into hi/lo bf16 (truncation; residual exact in fp32)
__device__ inline void splitf(float v, unsigned short& h, unsigned short& l) {
    unsigned b = __float_as_uint(v);
    h = (unsigned short)(b >> 16);
    float fh = __uint_as_float(b & 0xffff0000u);
    float r = v - fh;
    l = (unsigned short)(__float_as_uint(r) >> 16);
}

// ---------------- CSR build: rank-based counting sort (R11, kept) ----------------
// hist pass records per-edge rank within its (range,chunk,node) cell, so the
// fill pass is edge-parallel with no LDS/atomics and reads each edge ONCE.
// R12 post-mortem note: agg/GEMM fusion REVERTED -- merged kernel was
// latency-bound (Occ 15.8%, HBM 14%, 119us). Gather needs node-per-wave TLP.

__global__ __launch_bounds__(1024) void hist_rank(
    const int* __restrict__ dst, unsigned* __restrict__ hist,
    unsigned short* __restrict__ rank, int n_edges, int nchunk) {
    __shared__ unsigned lh[RSZ / 2];   // 16384 u16 counts packed in 8192 words, 32KB
    int b = blockIdx.x;
    int r = b & (NRANGE - 1), c = b >> 2;
    int t = threadIdx.x;
    for (int i = t; i < RSZ / 2; i += 1024) lh[i] = 0;
    __syncthreads();
    int e0 = c << CSH, e1 = min(n_edges, e0 + CSZ);
    for (int e = e0 + t; e < e1; e += 1024) {
        int d = dst[e];
        if ((d >> RSH) == r) {
            int ii = d & (RSZ - 1);
            unsigned sh = (ii & 1) * 16;
            unsigned old = atomicAdd(&lh[ii >> 1], 1u << sh);
            rank[e] = (unsigned short)((old >> sh) & 0xffffu);
        }
    }
    __syncthreads();
    unsigned* gh = hist + (size_t)(r * nchunk + c) * (RSZ / 2);
    for (int i = t; i < RSZ / 2; i += 1024) gh[i] = lh[i];
}

// ---------------- weight split+transpose args ----------------
struct WSplitArgs {
    const float* src[6];
    unsigned short* dh[6];
    unsigned short* dl[6];
};

// deg[i] = sum over chunks (u16 hist); block emits partial sum for the scan.
// Blocks >= nblk do the weight split+transpose (fused: saves a dispatch).
__global__ __launch_bounds__(256) void deg_splitw(
    const unsigned short* __restrict__ hist16, int* __restrict__ deg,
    int* __restrict__ partials, int n_nodes, int nchunk, int nblk, WSplitArgs a) {
    __shared__ int sd[256];
    int b = blockIdx.x, t = threadIdx.x;
    if (b >= nblk) {
        int g = (b - nblk) * 256 + t;
        int m, e, N;
        if (g < 65536) { m = g >> 14; e = g & 16383; N = 128; }
        else { int t2 = g - 65536; m = 4 + (t2 >> 13); e = t2 & 8191; N = 64; }
        int sh = (N == 128) ? 7 : 6;
        int k = e >> sh;
        int n = e & (N - 1);
        float v = a.src[m][e];
        unsigned short h, l;
        splitf(v, h, l);
        a.dh[m][n * 128 + k] = h;
        a.dl[m][n * 128 + k] = l;
        return;
    }
    int i = b * 256 + t;
    int s = 0;
    if (i < n_nodes) {
        int r = i >> RSH, ii = i & (RSZ - 1);
        const unsigned short* hp = hist16 + (size_t)r * nchunk * RSZ + ii;
        for (int c = 0; c < nchunk; ++c) s += hp[(size_t)c * RSZ];
        deg[i] = s;
    }
    sd[t] = s;
    __syncthreads();
    for (int st = 128; st > 0; st >>= 1) {
        if (t < st) sd[t] += sd[t + st];
        __syncthreads();
    }
    if (t == 0) partials[b] = sd[0];
}

// One block per 256 nodes: reduce partials locally, Hillis-Steele scan of deg,
// emit row_ptr + inv_deg, and fill base[] (per-cell exclusive offsets) in one pass.
__global__ __launch_bounds__(256) void scan_fill(
    const int* __restrict__ deg, const int* __restrict__ partials,
    const unsigned short* __restrict__ hist16, int* __restrict__ row_ptr,
    float* __restrict__ inv_deg, int* __restrict__ base,
    int n_nodes, int nchunk, int nblk) {
    __shared__ int sp[256];
    __shared__ int sd[256];
    int b = blockIdx.x, t = threadIdx.x;

    sp[t] = (t < b && t < nblk) ? partials[t] : 0;
    __syncthreads();
    for (int st = 128; st > 0; st >>= 1) {
        if (t < st) sp[t] += sp[t + st];
        __syncthreads();
    }
    int pbase = sp[0];

    int i = b * 256 + t;
    int v = (i < n_nodes) ? deg[i] : 0;
    sd[t] = v;
    __syncthreads();
    for (int d = 1; d < 256; d <<= 1) {
        int x = (t >= d) ? sd[t - d] : 0;
        __syncthreads();
        sd[t] += x;
        __syncthreads();
    }
    int excl = sd[t] - v + pbase;
    if (i < n_nodes) {
        row_ptr[i] = excl;
        int dv = v > 1 ? v : 1;
        inv_deg[i] = 1.0f / (float)dv;
        if (i == n_nodes - 1) row_ptr[n_nodes] = excl + v;
        int r = i >> RSH, ii = i & (RSZ - 1);
        int bacc = excl;
        for (int c = 0; c < nchunk; ++c) {
            size_t idx = (size_t)(r * nchunk + c) * RSZ + ii;
            base[idx] = bacc;
            bacc += hist16[idx];
        }
    }
}

// Edge-parallel, atomic-free fill: slot = base[cell] + rank[e].
__global__ __launch_bounds__(256) void fill_edges(
    const int* __restrict__ src, const int* __restrict__ dst,
    const unsigned short* __restrict__ rank, const int* __restrict__ base,
    int* __restrict__ csr, int n_edges, int nchunk) {
    int e = blockIdx.x * 256 + threadIdx.x;
    if (e >= n_edges) return;
    int d = dst[e];
    int c = e >> CSH;
    int r = d >> RSH;
    int slot = base[(size_t)(r * nchunk + c) * RSZ + (d & (RSZ - 1))] + rank[e];
    csr[slot] = src[e];
}

// ---------------- MFMA GEMM (LDS-staged, fused P+Q) -- R10 proven structure ----------------
// BM=64 rows/block, 4 waves. A-tile (hi+lo bf16) staged in LDS once per block.
// Wave w: matrix = w>>1 (0->P via W1, 1->Q via W2), col half = w&1.
// LDS layout [col16][row] stride 65 -> conflict-free ds_read_b128.
template <int BN, int NT, bool SPLITX>
__global__ __launch_bounds__(256) void gemm_lds(
    const float* __restrict__ X,
    const unsigned short* __restrict__ Ah, const unsigned short* __restrict__ Al,
    const unsigned short* __restrict__ W1h, const unsigned short* __restrict__ W1l,
    const unsigned short* __restrict__ W2h, const unsigned short* __restrict__ W2l,
    const float* __restrict__ bias, __half* __restrict__ P, float* __restrict__ Q, int M) {
    __shared__ short8 As[2][16 * 65];   // 33.3 KB

    const int tid = threadIdx.x;
    const int wave = tid >> 6;
    const int lane = tid & 63;
    const int l15 = lane & 15;
    const int q = lane >> 4;
    const int m0 = blockIdx.x * 64;

    if constexpr (SPLITX) {
#pragma unroll
        for (int it = 0; it < 4; ++it) {
            int s = it * 256 + tid;          // 0..1023
            int row = s >> 4, col16 = s & 15;
            int gr = min(m0 + row, M - 1);
            const float4* xp = (const float4*)X + (size_t)gr * 32 + col16 * 2;
            float4 v0 = xp[0], v1 = xp[1];
            float fv[8] = {v0.x, v0.y, v0.z, v0.w, v1.x, v1.y, v1.z, v1.w};
            short8 h, l;
#pragma unroll
            for (int j = 0; j < 8; ++j) {
                unsigned short hh_, ll_;
                splitf(fv[j], hh_, ll_);
                h[j] = (short)hh_;
                l[j] = (short)ll_;
            }
            As[0][col16 * 65 + row] = h;
            As[1][col16 * 65 + row] = l;
        }
    } else {
#pragma unroll
        for (int it = 0; it < 8; ++it) {
            int s = it * 256 + tid;          // 0..2047
            int arr = s >> 10;
            int sp = s & 1023;
            int row = sp >> 4, col16 = sp & 15;
            int gr = min(m0 + row, M - 1);
            const unsigned short* src = (arr ? Al : Ah) + (size_t)gr * 128 + col16 * 8;
            As[arr][col16 * 65 + row] = *(const short8*)src;
        }
    }
    __syncthreads();

    const int isQ = wave >> 1;
    const int colbase = (wave & 1) * (NT * 16);
    const unsigned short* Wh = isQ ? W2h : W1h;
    const unsigned short* Wl = isQ ? W2l : W1l;

    float bvs[NT];
#pragma unroll
    for (int nt = 0; nt < NT; ++nt) bvs[nt] = isQ ? bias[colbase + nt * 16 + l15] : 0.f;

    f32x4 acc[4][NT] = {};

#pragma unroll 1
    for (int kt = 0; kt < 4; ++kt) {
        short8 Bh[NT], Bl[NT];
#pragma unroll
        for (int nt = 0; nt < NT; ++nt) {
            int c = colbase + nt * 16 + l15;
            int off = c * 128 + kt * 32 + q * 8;
            Bh[nt] = *(const short8*)(Wh + off);
            Bl[nt] = *(const short8*)(Wl + off);
        }
#pragma unroll
        for (int mt = 0; mt < 4; ++mt) {
            int ai = (kt * 4 + q) * 65 + mt * 16 + l15;
            short8 Afh = As[0][ai];
            short8 Afl = As[1][ai];
#pragma unroll
            for (int nt = 0; nt < NT; ++nt) {
                acc[mt][nt] = __builtin_amdgcn_mfma_f32_16x16x32_bf16(Afh, Bh[nt], acc[mt][nt], 0, 0, 0);
                acc[mt][nt] = __builtin_amdgcn_mfma_f32_16x16x32_bf16(Afh, Bl[nt], acc[mt][nt], 0, 0, 0);
                acc[mt][nt] = __builtin_amdgcn_mfma_f32_16x16x32_bf16(Afl, Bh[nt], acc[mt][nt], 0, 0, 0);
            }
        }
    }

#pragma unroll
    for (int mt = 0; mt < 4; ++mt) {
        int orow = m0 + mt * 16 + q * 4;
#pragma unroll
        for (int nt = 0; nt < NT; ++nt) {
            int col = colbase + nt * 16 + l15;
#pragma unroll
            for (int r = 0; r < 4; ++r) {
                int rr = orow + r;
                if (rr < M) {
                    if (isQ) Q[(size_t)rr * BN + col] = acc[mt][nt][r] + bvs[nt];
                    else P[(size_t)rr * BN + col] = __float2half(acc[mt][nt][r]);
                }
            }
        }
    }
}

// ---------------- fused aggregation 128-dim, fp16 uint4 gather (node-per-wave TLP) ----------------
__global__ __launch_bounds__(256) void agg_fused128(
    const __half* __restrict__ P, const float* __restrict__ Q,
    const int* __restrict__ row_ptr, const int* __restrict__ csr,
    const float* __restrict__ inv_deg, unsigned short* __restrict__ Hh,
    unsigned short* __restrict__ Hl, int n_nodes) {
    int node = (blockIdx.x * blockDim.x + threadIdx.x) >> 6;
    int lane = threadIdx.x & 63;
    if (node >= n_nodes) return;
    int beg = row_ptr[node], end = row_ptr[node + 1];
    const int g = lane >> 4;    // edge slot 0..3
    const int l = lane & 15;    // 8-col group
    float a[2][8] = {};
    int e = beg;
    for (; e + 8 <= end; e += 8) {
#pragma unroll
        for (int j = 0; j < 2; ++j) {
            int s = csr[e + 4 * j + g];
            uint4 raw = *(const uint4*)(P + (size_t)s * 128 + l * 8);
            float2 f01 = __half22float2(*reinterpret_cast<__half2*>(&raw.x));
            float2 f23 = __half22float2(*reinterpret_cast<__half2*>(&raw.y));
            float2 f45 = __half22float2(*reinterpret_cast<__half2*>(&raw.z));
            float2 f67 = __half22float2(*reinterpret_cast<__half2*>(&raw.w));
            a[j][0] += f01.x; a[j][1] += f01.y; a[j][2] += f23.x; a[j][3] += f23.y;
            a[j][4] += f45.x; a[j][5] += f45.y; a[j][6] += f67.x; a[j][7] += f67.y;
        }
    }
    for (; e < end; e += 4) {
        int idx = e + g;
        if (idx < end) {
            int s = csr[idx];
            uint4 raw = *(const uint4*)(P + (size_t)s * 128 + l * 8);
            float2 f01 = __half22float2(*reinterpret_cast<__half2*>(&raw.x));
            float2 f23 = __half22float2(*reinterpret_cast<__half2*>(&raw.y));
            float2 f45 = __half22float2(*reinterpret_cast<__half2*>(&raw.z));
            float2 f67 = __half22float2(*reinterpret_cast<__half2*>(&raw.w));
            a[0][0] += f01.x; a[0][1] += f01.y; a[0][2] += f23.x; a[0][3] += f23.y;
            a[0][4] += f45.x; a[0][5] += f45.y; a[0][6] += f67.x; a[0][7] += f67.y;
        }
    }
    float s[8];
#pragma unroll
    for (int k = 0; k < 8; ++k) {
        s[k] = a[0][k] + a[1][k];
        s[k] += __shfl_xor(s[k], 16);
        s[k] += __shfl_xor(s[k], 32);
    }
    if (lane < 16) {
        float w = inv_deg[node];
        const float4* Q4 = (const float4*)Q;
        float4 q0 = Q4[(size_t)node * 32 + 2 * l];
        float4 q1 = Q4[(size_t)node * 32 + 2 * l + 1];
        float h0 = fmaxf(fmaf(s[0], w, q0.x), 0.f);
        float h1 = fmaxf(fmaf(s[1], w, q0.y), 0.f);
        float h2 = fmaxf(fmaf(s[2], w, q0.z), 0.f);
        float h3 = fmaxf(fmaf(s[3], w, q0.w), 0.f);
        float h4 = fmaxf(fmaf(s[4], w, q1.x), 0.f);
        float h5 = fmaxf(fmaf(s[5], w, q1.y), 0.f);
        float h6 = fmaxf(fmaf(s[6], w, q1.z), 0.f);
        float h7 = fmaxf(fmaf(s[7], w, q1.w), 0.f);
        ushort4 hv0, lv0, hv1, lv1;
        splitf(h0, hv0.x, lv0.x);
        splitf(h1, hv0.y, lv0.y);
        splitf(h2, hv0.z, lv0.z);
        splitf(h3, hv0.w, lv0.w);
        splitf(h4, hv1.x, lv1.x);
        splitf(h5, hv1.y, lv1.y);
        splitf(h6, hv1.z, lv1.z);
        splitf(h7, hv1.w, lv1.w);
        ((ushort4*)Hh)[(size_t)node * 32 + 2 * l] = hv0;
        ((ushort4*)Hh)[(size_t)node * 32 + 2 * l + 1] = hv1;
        ((ushort4*)Hl)[(size_t)node * 32 + 2 * l] = lv0;
        ((ushort4*)Hl)[(size_t)node * 32 + 2 * l + 1] = lv1;
    }
}

// ---------------- fused aggregation 64-dim (fp16 gather) + output head ----------------
__global__ __launch_bounds__(256) void agg64_head(
    const __half* __restrict__ P, const float* __restrict__ Q,
    const int* __restrict__ row_ptr, const int* __restrict__ csr,
    const float* __restrict__ inv_deg, const float* __restrict__ Wo,
    const float* __restrict__ bo, float* __restrict__ out, int n_nodes) {
    int node = (blockIdx.x * blockDim.x + threadIdx.x) >> 6;
    int lane = threadIdx.x & 63;
    if (node >= n_nodes) return;
    int beg = row_ptr[node], end = row_ptr[node + 1];
    const int quarter = lane >> 4;
    const int l = lane & 15;
    float a[2][4] = {};
    int e = beg;
    for (; e + 8 <= end; e += 8) {
#pragma unroll
        for (int j = 0; j < 2; ++j) {
            int s = csr[e + 4 * j + quarter];
            uint2 raw = *(const uint2*)(P + (size_t)s * 64 + l * 4);
            float2 f01 = __half22float2(*reinterpret_cast<__half2*>(&raw.x));
            float2 f23 = __half22float2(*reinterpret_cast<__half2*>(&raw.y));
            a[j][0] += f01.x; a[j][1] += f01.y; a[j][2] += f23.x; a[j][3] += f23.y;
        }
    }
    for (; e < end; e += 4) {
        int idx = e + quarter;
        if (idx < end) {
            int s = csr[idx];
            uint2 raw = *(const uint2*)(P + (size_t)s * 64 + l * 4);
            float2 f01 = __half22float2(*reinterpret_cast<__half2*>(&raw.x));
            float2 f23 = __half22float2(*reinterpret_cast<__half2*>(&raw.y));
            a[0][0] += f01.x; a[0][1] += f01.y; a[0][2] += f23.x; a[0][3] += f23.y;
        }
    }
    float s0 = a[0][0] + a[1][0];
    float s1 = a[0][1] + a[1][1];
    float s2 = a[0][2] + a[1][2];
    float s3 = a[0][3] + a[1][3];
    s0 += __shfl_xor(s0, 16); s0 += __shfl_xor(s0, 32);
    s1 += __shfl_xor(s1, 16); s1 += __shfl_xor(s1, 32);
    s2 += __shfl_xor(s2, 16); s2 += __shfl_xor(s2, 32);
    s3 += __shfl_xor(s3, 16); s3 += __shfl_xor(s3, 32);
    if (lane < 16) {
        float w = inv_deg[node];
        float4 qv = ((const float4*)Q)[(size_t)node * 16 + l];
        float h0 = fmaxf(fmaf(s0, w, qv.x), 0.f);
        float h1 = fmaxf(fmaf(s1, w, qv.y), 0.f);
        float h2 = fmaxf(fmaf(s2, w, qv.z), 0.f);
        float h3 = fmaxf(fmaf(s3, w, qv.w), 0.f);
        const float4* Wo4 = (const float4*)Wo;
        float4 w0 = Wo4[4 * l + 0], w1 = Wo4[4 * l + 1], w2 = Wo4[4 * l + 2], w3 = Wo4[4 * l + 3];
        float c0 = h0 * w0.x + h1 * w1.x + h2 * w2.x + h3 * w3.x;
        float c1 = h0 * w0.y + h1 * w1.y + h2 * w2.y + h3 * w3.y;
        float c2 = h0 * w0.z + h1 * w1.z + h2 * w2.z + h3 * w3.z;
        float c3 = h0 * w0.w + h1 * w1.w + h2 * w2.w + h3 * w3.w;
#pragma unroll
        for (int m = 8; m > 0; m >>= 1) {
            c0 += __shfl_xor(c0, m);
            c1 += __shfl_xor(c1, m);
            c2 += __shfl_xor(c2, m);
            c3 += __shfl_xor(c3, m);
        }
        if (l == 0) {
            float4 r;
            r.x = c0 + bo[0];
            r.y = c1 + bo[1];
            r.z = c2 + bo[2];
            r.w = c3 + bo[3];
            ((float4*)out)[node] = r;
        }
    }
}

extern "C" void kernel_launch(void* const* d_in, const int* in_sizes, int n_in,
                              void* d_out, int out_size, void* d_ws, size_t ws_size,
                              hipStream_t stream) {
    const float* x = (const float*)d_in[0];
    const int* ei = (const int*)d_in[1];
    const float* wl0 = (const float*)d_in[3];
    const float* wr0 = (const float*)d_in[4];
    const float* b0 = (const float*)d_in[5];
    const float* wl1 = (const float*)d_in[6];
    const float* wr1 = (const float*)d_in[7];
    const float* b1 = (const float*)d_in[8];
    const float* wl2 = (const float*)d_in[9];
    const float* wr2 = (const float*)d_in[10];
    const float* b2 = (const float*)d_in[11];
    const float* wo = (const float*)d_in[12];
    const float* bo = (const float*)d_in[13];

    const int n_nodes = in_sizes[0] / D;   // 50000
    const int n_edges = in_sizes[1] / 2;   // 800000
    const int* srcp = ei;
    const int* dstp = ei + n_edges;

    char* ws = (char*)d_ws;
    size_t off = 0;
    auto carve = [&](size_t bytes) -> void* {
        void* p = ws + off;
        off = (off + bytes + 255) & ~(size_t)255;
        return p;
    };
    int* deg = (int*)carve((size_t)n_nodes * 4);
    int* row_ptr = (int*)carve((size_t)(n_nodes + 1) * 4);
    int* partials = (int*)carve(256 * 4);
    float* inv_deg = (float*)carve((size_t)n_nodes * 4);
    unsigned short* rankb = (unsigned short*)carve((size_t)n_edges * 2);
    int* csr = (int*)carve((size_t)n_edges * 4);
    __half* Pbuf = (__half*)carve((size_t)n_nodes * D * 2);   // 12.8 MB
    float* Qbuf = (float*)carve((size_t)n_nodes * D * 4);     // 25.6 MB
    unsigned short* hh = (unsigned short*)carve((size_t)n_nodes * D * 2);
    unsigned short* hl = (unsigned short*)carve((size_t)n_nodes * D * 2);
    unsigned short* wt = (unsigned short*)carve((size_t)(4 * 128 * 128 + 2 * 64 * 128) * 2 * 2);
    unsigned short* wl0h = wt;
    unsigned short* wl0l = wl0h + 128 * 128;
    unsigned short* wr0h = wl0l + 128 * 128;
    unsigned short* wr0l = wr0h + 128 * 128;
    unsigned short* wl1h = wr0l + 128 * 128;
    unsigned short* wl1l = wl1h + 128 * 128;
    unsigned short* wr1h = wl1l + 128 * 128;
    unsigned short* wr1l = wr1h + 128 * 128;
    unsigned short* wl2h = wr1l + 128 * 128;
    unsigned short* wl2l = wl2h + 64 * 128;
    unsigned short* wr2h = wl2l + 64 * 128;
    unsigned short* wr2l = wr2h + 64 * 128;

    // CSR-build scratch aliases Pbuf/Qbuf (dead until first GEMM):
    const int nchunk = (n_edges + CSZ - 1) >> CSH;          // 25
    unsigned* hist = (unsigned*)Qbuf;                        // 4*25*16384*2B = 3.28 MB
    unsigned short* hist16 = (unsigned short*)Qbuf;
    int* basep = (int*)Pbuf;                                 // 6.55 MB

    const int nblk = (n_nodes + 255) / 256;                 // 196
    const int wblocks = (4 * 128 * 128 + 2 * 64 * 128) / 256;  // 320

    WSplitArgs wa;
    wa.src[0] = wl0; wa.dh[0] = wl0h; wa.dl[0] = wl0l;
    wa.src[1] = wr0; wa.dh[1] = wr0h; wa.dl[1] = wr0l;
    wa.src[2] = wl1; wa.dh[2] = wl1h; wa.dl[2] = wl1l;
    wa.src[3] = wr1; wa.dh[3] = wr1h; wa.dl[3] = wr1l;
    wa.src[4] = wl2; wa.dh[4] = wl2h; wa.dl[4] = wl2l;
    wa.src[5] = wr2; wa.dh[5] = wr2h; wa.dl[5] = wr2l;

    hist_rank<<<NRANGE * nchunk, 1024, 0, stream>>>(dstp, hist, rankb, n_edges, nchunk);
    deg_splitw<<<nblk + wblocks, 256, 0, stream>>>(hist16, deg, partials, n_nodes, nchunk, nblk, wa);
    scan_fill<<<nblk, 256, 0, stream>>>(deg, partials, hist16, row_ptr, inv_deg, basep,
                                        n_nodes, nchunk, nblk);
    fill_edges<<<(n_edges + 255) / 256, 256, 0, stream>>>(srcp, dstp, rankb, basep, csr,
                                                          n_edges, nchunk);

    const int agg_blocks = (n_nodes * 64 + 255) / 256;
    const int gemm_blocks = (n_nodes + 63) / 64;   // 782

    // layer 0: A = x (fp32, split during LDS staging)
    gemm_lds<128, 4, true><<<gemm_blocks, 256, 0, stream>>>(
        x, nullptr, nullptr, wl0h, wl0l, wr0h, wr0l, b0, Pbuf, Qbuf, n_nodes);
    agg_fused128<<<agg_blocks, 256, 0, stream>>>(Pbuf, Qbuf, row_ptr, csr, inv_deg, hh, hl, n_nodes);
    // layer 1
    gemm_lds<128, 4, false><<<gemm_blocks, 256, 0, stream>>>(
        nullptr, hh, hl, wl1h, wl1l, wr1h, wr1l, b1, Pbuf, Qbuf, n_nodes);
    agg_fused128<<<agg_blocks, 256, 0, stream>>>(Pbuf, Qbuf, row_ptr, csr, inv_deg, hh, hl, n_nodes);
    // layer 2 (each matrix 64 cols)
    gemm_lds<64, 2, false><<<gemm_blocks, 256, 0, stream>>>(
        nullptr, hh, hl, wl2h, wl2l, wr2h, wr2l, b2, Pbuf, Qbuf, n_nodes);
    agg64_head<<<agg_blocks, 256, 0, stream>>>(Pbuf, Qbuf, row_ptr, csr, inv_deg,
                                               wo, bo, (float*)d_out, n_nodes);
}

// Round 4
// 289.826 us; speedup vs baseline: 1.2641x; 1.0576x over previous
//
#include <hip/hip_runtime.h>
#include <hip/hip_fp16.h>

#define D 128

// CSR build geometry (pow-2 so kernels use shifts, not divides)
constexpr int RSH = 14;             // log2(range size)
constexpr int RSZ = 1 << RSH;       // 16384 nodes/range
constexpr int NRANGE = 4;           // ceil(50000/16384)
constexpr int CSH = 15;             // log2(chunk edges)
constexpr int CSZ = 1 << CSH;       // 32768 edges/chunk

using short8 = __attribute__((ext_vector_type(8))) short;
using f32x4 = __attribute__((ext_vector_type(4))) float;

// split fp32 into hi/lo bf16 (truncation; residual exact in fp32)
__device__ inline void splitf(float v, unsigned short& h, unsigned short& l) {
    unsigned b = __float_as_uint(v);
    h = (unsigned short)(b >> 16);
    float fh = __uint_as_float(b & 0xffff0000u);
    float r = v - fh;
    l = (unsigned short)(__float_as_uint(r) >> 16);
}

// ---------------- weight split+transpose: W[K=128][N] -> Wt_hi/lo [N][128] ----------------
struct WSplitArgs {
    const float* src[6];
    unsigned short* dh[6];
    unsigned short* dl[6];
    int n[6];
};

__global__ __launch_bounds__(256) void split_w(WSplitArgs a) {
    int m = blockIdx.y;
    int N = a.n[m];
    int e = blockIdx.x * 256 + threadIdx.x;
    if (e >= 128 * N) return;
    int sh = (N == 128) ? 7 : 6;
    int k = e >> sh;
    int n = e & (N - 1);
    float v = a.src[m][e];
    unsigned short h, l;
    splitf(v, h, l);
    a.dh[m][n * 128 + k] = h;
    a.dl[m][n * 128 + k] = l;
}

// ---------------- fused hist_rank (CSR phase 1) + layer-0 GEMM ----------------
// R13: hist uses only 100 blocks (~39% CU coverage); gemm_x is independent of the
// CSR build (needs only x + pre-split W0) -> pack both into ONE 1024-thread
// dispatch so gemm_x fills the idle CUs. Blocks [0,nhist): hist; rest: gemm tiles.
// gemm path: 16 waves, each 64 rows x 16 cols (NT=1); LDS A-tile union'd with
// hist's 32KB count array (33.3KB total).
__global__ __launch_bounds__(1024) void hist_gemm_x(
    const int* __restrict__ dst, unsigned* __restrict__ hist,
    unsigned short* __restrict__ rank, int n_edges, int nchunk, int nhist,
    const float* __restrict__ X,
    const unsigned short* __restrict__ W1h, const unsigned short* __restrict__ W1l,
    const unsigned short* __restrict__ W2h, const unsigned short* __restrict__ W2l,
    const float* __restrict__ bias, __half* __restrict__ P, float* __restrict__ Q, int M) {
    __shared__ __align__(16) char smem[2 * 16 * 65 * 16];   // 33280 B (hist needs 32768)

    const int b = blockIdx.x;
    const int tid = threadIdx.x;

    if (b < nhist) {
        // ---- hist_rank path ----
        unsigned* lh = (unsigned*)smem;   // RSZ/2 = 8192 words of packed u16 counts
        int r = b & (NRANGE - 1), c = b >> 2;
        for (int i = tid; i < RSZ / 2; i += 1024) lh[i] = 0;
        __syncthreads();
        int e0 = c << CSH, e1 = min(n_edges, e0 + CSZ);
        for (int e = e0 + tid; e < e1; e += 1024) {
            int d = dst[e];
            if ((d >> RSH) == r) {
                int ii = d & (RSZ - 1);
                unsigned sh = (ii & 1) * 16;
                unsigned old = atomicAdd(&lh[ii >> 1], 1u << sh);
                rank[e] = (unsigned short)((old >> sh) & 0xffffu);
            }
        }
        __syncthreads();
        unsigned* gh = hist + (size_t)(r * nchunk + c) * (RSZ / 2);
        for (int i = tid; i < RSZ / 2; i += 1024) gh[i] = lh[i];
        return;
    }

    // ---- gemm_x path ----
    short8(*As)[16 * 65] = (short8(*)[16 * 65])smem;
    const int wave = tid >> 6;          // 0..15
    const int lane = tid & 63;
    const int l15 = lane & 15;
    const int q = lane >> 4;
    const int m0 = (b - nhist) * 64;

    {   // stage A tile (64 rows x 128 cols fp32 -> bf16 hi/lo), 1024 slots exactly
        int row = tid >> 4, col16 = tid & 15;
        int gr = min(m0 + row, M - 1);
        const float4* xp = (const float4*)X + (size_t)gr * 32 + col16 * 2;
        float4 v0 = xp[0], v1 = xp[1];
        float fv[8] = {v0.x, v0.y, v0.z, v0.w, v1.x, v1.y, v1.z, v1.w};
        short8 h, l;
#pragma unroll
        for (int j = 0; j < 8; ++j) {
            unsigned short hh_, ll_;
            splitf(fv[j], hh_, ll_);
            h[j] = (short)hh_;
            l[j] = (short)ll_;
        }
        As[0][col16 * 65 + row] = h;
        As[1][col16 * 65 + row] = l;
    }
    __syncthreads();

    const int isQ = wave >> 3;                  // waves 0-7: P, 8-15: Q
    const int colbase = (wave & 7) * 16;
    const unsigned short* Wh = isQ ? W2h : W1h;
    const unsigned short* Wl = isQ ? W2l : W1l;
    const float bv = isQ ? bias[colbase + l15] : 0.f;

    f32x4 acc[4] = {};

#pragma unroll 1
    for (int kt = 0; kt < 4; ++kt) {
        int c = colbase + l15;
        int woff = c * 128 + kt * 32 + q * 8;
        short8 Bh = *(const short8*)(Wh + woff);
        short8 Bl = *(const short8*)(Wl + woff);
#pragma unroll
        for (int mt = 0; mt < 4; ++mt) {
            int ai = (kt * 4 + q) * 65 + mt * 16 + l15;
            short8 Afh = As[0][ai];
            short8 Afl = As[1][ai];
            acc[mt] = __builtin_amdgcn_mfma_f32_16x16x32_bf16(Afh, Bh, acc[mt], 0, 0, 0);
            acc[mt] = __builtin_amdgcn_mfma_f32_16x16x32_bf16(Afh, Bl, acc[mt], 0, 0, 0);
            acc[mt] = __builtin_amdgcn_mfma_f32_16x16x32_bf16(Afl, Bh, acc[mt], 0, 0, 0);
        }
    }

#pragma unroll
    for (int mt = 0; mt < 4; ++mt) {
        int orow = m0 + mt * 16 + q * 4;
        int col = colbase + l15;
#pragma unroll
        for (int r = 0; r < 4; ++r) {
            int rr = orow + r;
            if (rr < M) {
                if (isQ) Q[(size_t)rr * 128 + col] = acc[mt][r] + bv;
                else P[(size_t)rr * 128 + col] = __float2half(acc[mt][r]);
            }
        }
    }
}

// deg[i] = sum over chunks (u16 hist); block emits partial sum for the scan.
__global__ __launch_bounds__(256) void deg_sum_partials(
    const unsigned short* __restrict__ hist16, int* __restrict__ deg,
    int* __restrict__ partials, int n_nodes, int nchunk) {
    __shared__ int sd[256];
    int b = blockIdx.x, t = threadIdx.x;
    int i = b * 256 + t;
    int s = 0;
    if (i < n_nodes) {
        int r = i >> RSH, ii = i & (RSZ - 1);
        const unsigned short* hp = hist16 + (size_t)r * nchunk * RSZ + ii;
        for (int c = 0; c < nchunk; ++c) s += hp[(size_t)c * RSZ];
        deg[i] = s;
    }
    sd[t] = s;
    __syncthreads();
    for (int st = 128; st > 0; st >>= 1) {
        if (t < st) sd[t] += sd[t + st];
        __syncthreads();
    }
    if (t == 0) partials[b] = sd[0];
}

// One block per 256 nodes: reduce partials locally, Hillis-Steele scan of deg,
// emit row_ptr + inv_deg, and fill base[] (per-cell exclusive offsets) in one pass.
__global__ __launch_bounds__(256) void scan_fill(
    const int* __restrict__ deg, const int* __restrict__ partials,
    const unsigned short* __restrict__ hist16, int* __restrict__ row_ptr,
    float* __restrict__ inv_deg, int* __restrict__ base,
    int n_nodes, int nchunk, int nblk) {
    __shared__ int sp[256];
    __shared__ int sd[256];
    int b = blockIdx.x, t = threadIdx.x;

    sp[t] = (t < b && t < nblk) ? partials[t] : 0;
    __syncthreads();
    for (int st = 128; st > 0; st >>= 1) {
        if (t < st) sp[t] += sp[t + st];
        __syncthreads();
    }
    int pbase = sp[0];

    int i = b * 256 + t;
    int v = (i < n_nodes) ? deg[i] : 0;
    sd[t] = v;
    __syncthreads();
    for (int d = 1; d < 256; d <<= 1) {
        int x = (t >= d) ? sd[t - d] : 0;
        __syncthreads();
        sd[t] += x;
        __syncthreads();
    }
    int excl = sd[t] - v + pbase;
    if (i < n_nodes) {
        row_ptr[i] = excl;
        int dv = v > 1 ? v : 1;
        inv_deg[i] = 1.0f / (float)dv;
        if (i == n_nodes - 1) row_ptr[n_nodes] = excl + v;
        int r = i >> RSH, ii = i & (RSZ - 1);
        int bacc = excl;
        for (int c = 0; c < nchunk; ++c) {
            size_t idx = (size_t)(r * nchunk + c) * RSZ + ii;
            base[idx] = bacc;
            bacc += hist16[idx];
        }
    }
}

// Edge-parallel, atomic-free fill: slot = base[cell] + rank[e].
__global__ __launch_bounds__(256) void fill_edges(
    const int* __restrict__ src, const int* __restrict__ dst,
    const unsigned short* __restrict__ rank, const int* __restrict__ base,
    int* __restrict__ csr, int n_edges, int nchunk) {
    int e = blockIdx.x * 256 + threadIdx.x;
    if (e >= n_edges) return;
    int d = dst[e];
    int c = e >> CSH;
    int r = d >> RSH;
    int slot = base[(size_t)(r * nchunk + c) * RSZ + (d & (RSZ - 1))] + rank[e];
    csr[slot] = src[e];
}

// ---------------- MFMA GEMM (LDS-staged, fused P+Q) -- layers 1,2 ----------------
template <int BN, int NT>
__global__ __launch_bounds__(256) void gemm_lds(
    const unsigned short* __restrict__ Ah, const unsigned short* __restrict__ Al,
    const unsigned short* __restrict__ W1h, const unsigned short* __restrict__ W1l,
    const unsigned short* __restrict__ W2h, const unsigned short* __restrict__ W2l,
    const float* __restrict__ bias, __half* __restrict__ P, float* __restrict__ Q, int M) {
    __shared__ short8 As[2][16 * 65];   // 33.3 KB

    const int tid = threadIdx.x;
    const int wave = tid >> 6;
    const int lane = tid & 63;
    const int l15 = lane & 15;
    const int q = lane >> 4;
    const int m0 = blockIdx.x * 64;

#pragma unroll
    for (int it = 0; it < 8; ++it) {
        int s = it * 256 + tid;          // 0..2047
        int arr = s >> 10;
        int sp = s & 1023;
        int row = sp >> 4, col16 = sp & 15;
        int gr = min(m0 + row, M - 1);
        const unsigned short* src = (arr ? Al : Ah) + (size_t)gr * 128 + col16 * 8;
        As[arr][col16 * 65 + row] = *(const short8*)src;
    }
    __syncthreads();

    const int isQ = wave >> 1;
    const int colbase = (wave & 1) * (NT * 16);
    const unsigned short* Wh = isQ ? W2h : W1h;
    const unsigned short* Wl = isQ ? W2l : W1l;

    float bvs[NT];
#pragma unroll
    for (int nt = 0; nt < NT; ++nt) bvs[nt] = isQ ? bias[colbase + nt * 16 + l15] : 0.f;

    f32x4 acc[4][NT] = {};

#pragma unroll 1
    for (int kt = 0; kt < 4; ++kt) {
        short8 Bh[NT], Bl[NT];
#pragma unroll
        for (int nt = 0; nt < NT; ++nt) {
            int c = colbase + nt * 16 + l15;
            int off = c * 128 + kt * 32 + q * 8;
            Bh[nt] = *(const short8*)(Wh + off);
            Bl[nt] = *(const short8*)(Wl + off);
        }
#pragma unroll
        for (int mt = 0; mt < 4; ++mt) {
            int ai = (kt * 4 + q) * 65 + mt * 16 + l15;
            short8 Afh = As[0][ai];
            short8 Afl = As[1][ai];
#pragma unroll
            for (int nt = 0; nt < NT; ++nt) {
                acc[mt][nt] = __builtin_amdgcn_mfma_f32_16x16x32_bf16(Afh, Bh[nt], acc[mt][nt], 0, 0, 0);
                acc[mt][nt] = __builtin_amdgcn_mfma_f32_16x16x32_bf16(Afh, Bl[nt], acc[mt][nt], 0, 0, 0);
                acc[mt][nt] = __builtin_amdgcn_mfma_f32_16x16x32_bf16(Afl, Bh[nt], acc[mt][nt], 0, 0, 0);
            }
        }
    }

#pragma unroll
    for (int mt = 0; mt < 4; ++mt) {
        int orow = m0 + mt * 16 + q * 4;
#pragma unroll
        for (int nt = 0; nt < NT; ++nt) {
            int col = colbase + nt * 16 + l15;
#pragma unroll
            for (int r = 0; r < 4; ++r) {
                int rr = orow + r;
                if (rr < M) {
                    if (isQ) Q[(size_t)rr * BN + col] = acc[mt][nt][r] + bvs[nt];
                    else P[(size_t)rr * BN + col] = __float2half(acc[mt][nt][r]);
                }
            }
        }
    }
}

// ---------------- fused aggregation 128-dim, fp16 uint4 gather ----------------
// R13: csr indices for the NEXT 8-edge group prefetched during the current
// group's gathers -- breaks the index-load -> gather serial chain.
__global__ __launch_bounds__(256) void agg_fused128(
    const __half* __restrict__ P, const float* __restrict__ Q,
    const int* __restrict__ row_ptr, const int* __restrict__ csr,
    const float* __restrict__ inv_deg, unsigned short* __restrict__ Hh,
    unsigned short* __restrict__ Hl, int n_nodes) {
    int node = (blockIdx.x * blockDim.x + threadIdx.x) >> 6;
    int lane = threadIdx.x & 63;
    if (node >= n_nodes) return;
    int beg = row_ptr[node], end = row_ptr[node + 1];
    const int g = lane >> 4;    // edge slot 0..3
    const int l = lane & 15;    // 8-col group
    float a[2][8] = {};
    int e = beg;
    bool have = (e + 8 <= end);
    int i0 = 0, i1 = 0;
    if (have) { i0 = csr[e + g]; i1 = csr[e + 4 + g]; }
    while (have) {
        int en = e + 8;
        bool hn = (en + 8 <= end);
        int n0 = 0, n1 = 0;
        if (hn) { n0 = csr[en + g]; n1 = csr[en + 4 + g]; }
        int ss[2] = {i0, i1};
#pragma unroll
        for (int j = 0; j < 2; ++j) {
            uint4 raw = *(const uint4*)(P + (size_t)ss[j] * 128 + l * 8);
            float2 f01 = __half22float2(*reinterpret_cast<__half2*>(&raw.x));
            float2 f23 = __half22float2(*reinterpret_cast<__half2*>(&raw.y));
            float2 f45 = __half22float2(*reinterpret_cast<__half2*>(&raw.z));
            float2 f67 = __half22float2(*reinterpret_cast<__half2*>(&raw.w));
            a[j][0] += f01.x; a[j][1] += f01.y; a[j][2] += f23.x; a[j][3] += f23.y;
            a[j][4] += f45.x; a[j][5] += f45.y; a[j][6] += f67.x; a[j][7] += f67.y;
        }
        e = en; i0 = n0; i1 = n1; have = hn;
    }
    for (; e < end; e += 4) {
        int idx = e + g;
        if (idx < end) {
            int s = csr[idx];
            uint4 raw = *(const uint4*)(P + (size_t)s * 128 + l * 8);
            float2 f01 = __half22float2(*reinterpret_cast<__half2*>(&raw.x));
            float2 f23 = __half22float2(*reinterpret_cast<__half2*>(&raw.y));
            float2 f45 = __half22float2(*reinterpret_cast<__half2*>(&raw.z));
            float2 f67 = __half22float2(*reinterpret_cast<__half2*>(&raw.w));
            a[0][0] += f01.x; a[0][1] += f01.y; a[0][2] += f23.x; a[0][3] += f23.y;
            a[0][4] += f45.x; a[0][5] += f45.y; a[0][6] += f67.x; a[0][7] += f67.y;
        }
    }
    float s[8];
#pragma unroll
    for (int k = 0; k < 8; ++k) {
        s[k] = a[0][k] + a[1][k];
        s[k] += __shfl_xor(s[k], 16);
        s[k] += __shfl_xor(s[k], 32);
    }
    if (lane < 16) {
        float w = inv_deg[node];
        const float4* Q4 = (const float4*)Q;
        float4 q0 = Q4[(size_t)node * 32 + 2 * l];
        float4 q1 = Q4[(size_t)node * 32 + 2 * l + 1];
        float h0 = fmaxf(fmaf(s[0], w, q0.x), 0.f);
        float h1 = fmaxf(fmaf(s[1], w, q0.y), 0.f);
        float h2 = fmaxf(fmaf(s[2], w, q0.z), 0.f);
        float h3 = fmaxf(fmaf(s[3], w, q0.w), 0.f);
        float h4 = fmaxf(fmaf(s[4], w, q1.x), 0.f);
        float h5 = fmaxf(fmaf(s[5], w, q1.y), 0.f);
        float h6 = fmaxf(fmaf(s[6], w, q1.z), 0.f);
        float h7 = fmaxf(fmaf(s[7], w, q1.w), 0.f);
        ushort4 hv0, lv0, hv1, lv1;
        splitf(h0, hv0.x, lv0.x);
        splitf(h1, hv0.y, lv0.y);
        splitf(h2, hv0.z, lv0.z);
        splitf(h3, hv0.w, lv0.w);
        splitf(h4, hv1.x, lv1.x);
        splitf(h5, hv1.y, lv1.y);
        splitf(h6, hv1.z, lv1.z);
        splitf(h7, hv1.w, lv1.w);
        ((ushort4*)Hh)[(size_t)node * 32 + 2 * l] = hv0;
        ((ushort4*)Hh)[(size_t)node * 32 + 2 * l + 1] = hv1;
        ((ushort4*)Hl)[(size_t)node * 32 + 2 * l] = lv0;
        ((ushort4*)Hl)[(size_t)node * 32 + 2 * l + 1] = lv1;
    }
}

// ---------------- fused aggregation 64-dim (fp16 gather) + output head ----------------
__global__ __launch_bounds__(256) void agg64_head(
    const __half* __restrict__ P, const float* __restrict__ Q,
    const int* __restrict__ row_ptr, const int* __restrict__ csr,
    const float* __restrict__ inv_deg, const float* __restrict__ Wo,
    const float* __restrict__ bo, float* __restrict__ out, int n_nodes) {
    int node = (blockIdx.x * blockDim.x + threadIdx.x) >> 6;
    int lane = threadIdx.x & 63;
    if (node >= n_nodes) return;
    int beg = row_ptr[node], end = row_ptr[node + 1];
    const int quarter = lane >> 4;
    const int l = lane & 15;
    float a[2][4] = {};
    int e = beg;
    bool have = (e + 8 <= end);
    int i0 = 0, i1 = 0;
    if (have) { i0 = csr[e + quarter]; i1 = csr[e + 4 + quarter]; }
    while (have) {
        int en = e + 8;
        bool hn = (en + 8 <= end);
        int n0 = 0, n1 = 0;
        if (hn) { n0 = csr[en + quarter]; n1 = csr[en + 4 + quarter]; }
        int ss[2] = {i0, i1};
#pragma unroll
        for (int j = 0; j < 2; ++j) {
            uint2 raw = *(const uint2*)(P + (size_t)ss[j] * 64 + l * 4);
            float2 f01 = __half22float2(*reinterpret_cast<__half2*>(&raw.x));
            float2 f23 = __half22float2(*reinterpret_cast<__half2*>(&raw.y));
            a[j][0] += f01.x; a[j][1] += f01.y; a[j][2] += f23.x; a[j][3] += f23.y;
        }
        e = en; i0 = n0; i1 = n1; have = hn;
    }
    for (; e < end; e += 4) {
        int idx = e + quarter;
        if (idx < end) {
            int s = csr[idx];
            uint2 raw = *(const uint2*)(P + (size_t)s * 64 + l * 4);
            float2 f01 = __half22float2(*reinterpret_cast<__half2*>(&raw.x));
            float2 f23 = __half22float2(*reinterpret_cast<__half2*>(&raw.y));
            a[0][0] += f01.x; a[0][1] += f01.y; a[0][2] += f23.x; a[0][3] += f23.y;
        }
    }
    float s0 = a[0][0] + a[1][0];
    float s1 = a[0][1] + a[1][1];
    float s2 = a[0][2] + a[1][2];
    float s3 = a[0][3] + a[1][3];
    s0 += __shfl_xor(s0, 16); s0 += __shfl_xor(s0, 32);
    s1 += __shfl_xor(s1, 16); s1 += __shfl_xor(s1, 32);
    s2 += __shfl_xor(s2, 16); s2 += __shfl_xor(s2, 32);
    s3 += __shfl_xor(s3, 16); s3 += __shfl_xor(s3, 32);
    if (lane < 16) {
        float w = inv_deg[node];
        float4 qv = ((const float4*)Q)[(size_t)node * 16 + l];
        float h0 = fmaxf(fmaf(s0, w, qv.x), 0.f);
        float h1 = fmaxf(fmaf(s1, w, qv.y), 0.f);
        float h2 = fmaxf(fmaf(s2, w, qv.z), 0.f);
        float h3 = fmaxf(fmaf(s3, w, qv.w), 0.f);
        const float4* Wo4 = (const float4*)Wo;
        float4 w0 = Wo4[4 * l + 0], w1 = Wo4[4 * l + 1], w2 = Wo4[4 * l + 2], w3 = Wo4[4 * l + 3];
        float c0 = h0 * w0.x + h1 * w1.x + h2 * w2.x + h3 * w3.x;
        float c1 = h0 * w0.y + h1 * w1.y + h2 * w2.y + h3 * w3.y;
        float c2 = h0 * w0.z + h1 * w1.z + h2 * w2.z + h3 * w3.z;
        float c3 = h0 * w0.w + h1 * w1.w + h2 * w2.w + h3 * w3.w;
#pragma unroll
        for (int m = 8; m > 0; m >>= 1) {
            c0 += __shfl_xor(c0, m);
            c1 += __shfl_xor(c1, m);
            c2 += __shfl_xor(c2, m);
            c3 += __shfl_xor(c3, m);
        }
        if (l == 0) {
            float4 r;
            r.x = c0 + bo[0];
            r.y = c1 + bo[1];
            r.z = c2 + bo[2];
            r.w = c3 + bo[3];
            ((float4*)out)[node] = r;
        }
    }
}

extern "C" void kernel_launch(void* const* d_in, const int* in_sizes, int n_in,
                              void* d_out, int out_size, void* d_ws, size_t ws_size,
                              hipStream_t stream) {
    const float* x = (const float*)d_in[0];
    const int* ei = (const int*)d_in[1];
    const float* wl0 = (const float*)d_in[3];
    const float* wr0 = (const float*)d_in[4];
    const float* b0 = (const float*)d_in[5];
    const float* wl1 = (const float*)d_in[6];
    const float* wr1 = (const float*)d_in[7];
    const float* b1 = (const float*)d_in[8];
    const float* wl2 = (const float*)d_in[9];
    const float* wr2 = (const float*)d_in[10];
    const float* b2 = (const float*)d_in[11];
    const float* wo = (const float*)d_in[12];
    const float* bo = (const float*)d_in[13];

    const int n_nodes = in_sizes[0] / D;   // 50000
    const int n_edges = in_sizes[1] / 2;   // 800000
    const int* srcp = ei;
    const int* dstp = ei + n_edges;

    char* ws = (char*)d_ws;
    size_t off = 0;
    auto carve = [&](size_t bytes) -> void* {
        void* p = ws + off;
        off = (off + bytes + 255) & ~(size_t)255;
        return p;
    };
    int* deg = (int*)carve((size_t)n_nodes * 4);
    int* row_ptr = (int*)carve((size_t)(n_nodes + 1) * 4);
    int* partials = (int*)carve(256 * 4);
    float* inv_deg = (float*)carve((size_t)n_nodes * 4);
    unsigned short* rankb = (unsigned short*)carve((size_t)n_edges * 2);
    int* csr = (int*)carve((size_t)n_edges * 4);
    __half* Pbuf = (__half*)carve((size_t)n_nodes * D * 2);   // 12.8 MB
    float* Qbuf = (float*)carve((size_t)n_nodes * D * 4);     // 25.6 MB
    unsigned short* hh = (unsigned short*)carve((size_t)n_nodes * D * 2);
    unsigned short* hl = (unsigned short*)carve((size_t)n_nodes * D * 2);
    unsigned short* wt = (unsigned short*)carve((size_t)(4 * 128 * 128 + 2 * 64 * 128) * 2 * 2);
    unsigned short* wl0h = wt;
    unsigned short* wl0l = wl0h + 128 * 128;
    unsigned short* wr0h = wl0l + 128 * 128;
    unsigned short* wr0l = wr0h + 128 * 128;
    unsigned short* wl1h = wr0l + 128 * 128;
    unsigned short* wl1l = wl1h + 128 * 128;
    unsigned short* wr1h = wl1l + 128 * 128;
    unsigned short* wr1l = wr1h + 128 * 128;
    unsigned short* wl2h = wr1l + 128 * 128;
    unsigned short* wl2l = wl2h + 64 * 128;
    unsigned short* wr2h = wl2l + 64 * 128;
    unsigned short* wr2l = wr2h + 64 * 128;

    // R13: hist/base in DEDICATED scratch (no P/Q aliasing) so gemm_x can run
    // concurrently with hist in the fused dispatch.
    const int nchunk = (n_edges + CSZ - 1) >> CSH;          // 25
    unsigned* hist = (unsigned*)carve((size_t)NRANGE * nchunk * (RSZ / 2) * 4);   // 3.3 MB
    unsigned short* hist16 = (unsigned short*)hist;
    int* basep = (int*)carve((size_t)NRANGE * nchunk * RSZ * 4);                  // 6.6 MB

    const int nblk = (n_nodes + 255) / 256;                 // 196
    const int nhist = NRANGE * nchunk;                      // 100
    const int gemm_blocks = (n_nodes + 63) / 64;            // 782
    const int agg_blocks = (n_nodes * 64 + 255) / 256;

    WSplitArgs wa;
    wa.src[0] = wl0; wa.dh[0] = wl0h; wa.dl[0] = wl0l; wa.n[0] = 128;
    wa.src[1] = wr0; wa.dh[1] = wr0h; wa.dl[1] = wr0l; wa.n[1] = 128;
    wa.src[2] = wl1; wa.dh[2] = wl1h; wa.dl[2] = wl1l; wa.n[2] = 128;
    wa.src[3] = wr1; wa.dh[3] = wr1h; wa.dl[3] = wr1l; wa.n[3] = 128;
    wa.src[4] = wl2; wa.dh[4] = wl2h; wa.dl[4] = wl2l; wa.n[4] = 64;
    wa.src[5] = wr2; wa.dh[5] = wr2h; wa.dl[5] = wr2l; wa.n[5] = 64;

    // 1. split weights (tiny; gemm_x depends on W0 split)
    split_w<<<dim3(64, 6), 256, 0, stream>>>(wa);
    // 2. hist (CSR phase 1, 100 blocks) || layer-0 GEMM (782 blocks)
    hist_gemm_x<<<nhist + gemm_blocks, 1024, 0, stream>>>(
        dstp, hist, rankb, n_edges, nchunk, nhist,
        x, wl0h, wl0l, wr0h, wr0l, b0, Pbuf, Qbuf, n_nodes);
    // 3-5. rest of CSR build
    deg_sum_partials<<<nblk, 256, 0, stream>>>(hist16, deg, partials, n_nodes, nchunk);
    scan_fill<<<nblk, 256, 0, stream>>>(deg, partials, hist16, row_ptr, inv_deg, basep,
                                        n_nodes, nchunk, nblk);
    fill_edges<<<(n_edges + 255) / 256, 256, 0, stream>>>(srcp, dstp, rankb, basep, csr,
                                                          n_edges, nchunk);
    // 6-10. layers
    agg_fused128<<<agg_blocks, 256, 0, stream>>>(Pbuf, Qbuf, row_ptr, csr, inv_deg, hh, hl, n_nodes);
    gemm_lds<128, 4><<<gemm_blocks, 256, 0, stream>>>(
        hh, hl, wl1h, wl1l, wr1h, wr1l, b1, Pbuf, Qbuf, n_nodes);
    agg_fused128<<<agg_blocks, 256, 0, stream>>>(Pbuf, Qbuf, row_ptr, csr, inv_deg, hh, hl, n_nodes);
    gemm_lds<64, 2><<<gemm_blocks, 256, 0, stream>>>(
        hh, hl, wl2h, wl2l, wr2h, wr2l, b2, Pbuf, Qbuf, n_nodes);
    agg64_head<<<agg_blocks, 256, 0, stream>>>(Pbuf, Qbuf, row_ptr, csr, inv_deg,
                                               wo, bo, (float*)d_out, n_nodes);
}